// Round 1
// baseline (307.672 us; speedup 1.0000x reference)
//
#include <hip/hip_runtime.h>

// BNMorph forward, sparse-scatter formulation.
// B=8, H=320, W=1024. Outputs (concat, f32, each [B,H,W]):
//   0 morphedx, 1 morphedy, 2 orgpts_x, 3 orgpts_y, 4 correspts_x, 5 correspts_y

#define BB 8
#define HH 320
#define WW 1024
#define N_PIX (BB*HH*WW)          // 2,621,440
#define RR 20                      // sense radius
#define KW 41                      // kernel width (2R+1)
#define TILE 32
#define TILES_X (WW/TILE)          // 32
#define TILES_Y (HH/TILE)          // 10
#define TILES_PER_B (TILES_X*TILES_Y)   // 320
#define N_TILES (BB*TILES_PER_B)   // 2560
#define NQ 105                     // search offsets
#define CAP_MAX 512                // per-tile point capacity (LDS array bound)
#define LISTS_OFF 16384            // byte offset of lists in d_ws (cnt first)

__global__ __launch_bounds__(256) void zero_counters(int* __restrict__ cnt) {
    int i = blockIdx.x * 256 + threadIdx.x;
    if (i < N_TILES) cnt[i] = 0;
}

// One thread per pixel. Sparsity filter + windowed first-hit search.
// Writes outputs 2..5 densely; appends packed found-points to tile lists.
__global__ __launch_bounds__(256) void build_points(
    const float* __restrict__ src, const float* __restrict__ dst,
    const float* __restrict__ xx, const float* __restrict__ yy,
    float* __restrict__ out, int* __restrict__ cnt,
    unsigned* __restrict__ lists, int cap)
{
    __shared__ int sdx[NQ], sdy[NQ];
    int t = threadIdx.x;
    if (t < NQ) { sdx[t] = (int)xx[t]; sdy[t] = (int)yy[t]; }
    __syncthreads();

    int x = blockIdx.x * 256 + t;
    int y = blockIdx.y;
    int b = blockIdx.z;
    const float* sb = src + (size_t)b * HH * WW;
    const float* db = dst + (size_t)b * HH * WW;

    bool active = sb[y * WW + x] > 0.5f;

    // precedence window: dy in [-2,-1] x dx in [-2,2]; dy==0 x dx in [-2,-1]
    bool kept = active;
    if (active) {
        const int ody[12] = {-2,-2,-2,-2,-2,-1,-1,-1,-1,-1, 0, 0};
        const int odx[12] = {-2,-1, 0, 1, 2,-2,-1, 0, 1, 2,-2,-1};
        bool blocked = false;
        #pragma unroll
        for (int k = 0; k < 12; ++k) {
            int y2 = y + ody[k], x2 = x + odx[k];
            bool inb = (y2 >= 0) & (x2 >= 0) & (x2 < WW);   // y2<=y<HH always
            if (inb && sb[y2 * WW + x2] > 0.5f) blocked = true;
        }
        kept = !blocked;
    }

    bool found = false; int vx = 0, vy = 0;
    if (kept) {
        for (int k = 0; k < NQ; ++k) {   // offsets pre-sorted by distance
            int dx = sdx[k], dy = sdy[k];
            int x2 = x + dx, y2 = y + dy;
            if (x2 < 0 || x2 >= WW || y2 < 0 || y2 >= HH) continue;  // zero pad
            if (db[y2 * WW + x2] > 0.5f) { found = true; vx = dx; vy = dy; break; }
        }
    }

    float m  = found ? 1.0f : 0.0f;
    float fx = (float)x, fy = (float)y;
    size_t base = (size_t)b * HH * WW + (size_t)y * WW + x;
    out[2 * (size_t)N_PIX + base] = fx * m;
    out[3 * (size_t)N_PIX + base] = fy * m;
    out[4 * (size_t)N_PIX + base] = (fx + (float)vx) * m;
    out[5 * (size_t)N_PIX + base] = (fy + (float)vy) * m;

    if (found) {
        unsigned pk = (unsigned)x | ((unsigned)y << 10)
                    | ((unsigned)(vx + 7) << 19) | ((unsigned)(vy + 3) << 23);
        int txl = x - RR; txl = (txl < 0 ? 0 : txl) >> 5;
        int txh = x + RR; txh = (txh > WW - 1 ? WW - 1 : txh) >> 5;
        int tyl = y - RR; tyl = (tyl < 0 ? 0 : tyl) >> 5;
        int tyh = y + RR; tyh = (tyh > HH - 1 ? HH - 1 : tyh) >> 5;
        for (int ty = tyl; ty <= tyh; ++ty)
            for (int tx = txl; tx <= txh; ++tx) {
                int tile = b * TILES_PER_B + ty * TILES_X + tx;
                int pos = atomicAdd(&cnt[tile], 1);
                if (pos < cap) lists[(size_t)tile * cap + pos] = pk;
            }
    }
}

// One block per 32x32 tile. Accumulate splat from the tile's point list,
// then finalize morphedx/morphedy.
__global__ __launch_bounds__(256) void splat_finalize(
    const int* __restrict__ cnt, const unsigned* __restrict__ lists,
    float* __restrict__ out, int cap)
{
    __shared__ float wtab[KW * KW];
    __shared__ unsigned pts[CAP_MAX];
    int t = threadIdx.x;

    // build weight table: K[dy+R][dx+R] = 0.7*exp(-sqrt(dx^2+dy^2)*1.9/24)
    for (int i = t; i < KW * KW; i += 256) {
        int dy = i / KW - RR, dx = i % KW - RR;
        float d = sqrtf((float)(dx * dx + dy * dy));
        wtab[i] = 0.7f * expf((-d * 1.9f) / 24.0f);
    }

    int tx = blockIdx.x, ty = blockIdx.y, b = blockIdx.z;
    int tile = b * TILES_PER_B + ty * TILES_X + tx;
    int n = cnt[tile]; if (n > cap) n = cap;
    for (int i = t; i < n; i += 256) pts[i] = lists[(size_t)tile * cap + i];
    __syncthreads();

    int lx = t & 31, ly = t >> 5;          // thread covers rows ly+8i, i=0..3
    int x  = tx * TILE + lx;
    int y0 = ty * TILE + ly;

    float a0[4] = {0,0,0,0}, a1[4] = {0,0,0,0}, a2[4] = {0,0,0,0};
    for (int p = 0; p < n; ++p) {
        unsigned pk = pts[p];
        int px = pk & 1023;
        int py = (pk >> 10) & 511;
        float pvx = (float)((int)((pk >> 19) & 15) - 7);
        float pvy = (float)((int)((pk >> 23) & 7) - 3);
        int dx = px - x;
        unsigned udx = (unsigned)(dx + RR);
        bool okx = (udx <= 2 * RR);
        int dy0 = py - y0;
        #pragma unroll
        for (int i = 0; i < 4; ++i) {
            unsigned udy = (unsigned)(dy0 - 8 * i + RR);
            bool ok = okx & (udy <= 2 * RR);
            int wi = ok ? (int)(udy * KW + udx) : 0;   // clamped, in-bounds
            float w = wtab[wi];
            w = ok ? w : 0.0f;
            a0[i] += w;
            a1[i] += w * pvx;
            a2[i] += w * pvy;
        }
    }

    size_t bbase = (size_t)b * HH * WW;
    #pragma unroll
    for (int i = 0; i < 4; ++i) {
        int y = y0 + 8 * i;
        size_t idx = bbase + (size_t)y * WW + x;
        float den   = a0[i] + 1.6f;
        float dispx = a1[i] / den;
        float dispy = a2[i] / den;
        out[idx]                  = (float)x + dispx;
        out[(size_t)N_PIX + idx]  = (float)y + dispy;
    }
}

extern "C" void kernel_launch(void* const* d_in, const int* in_sizes, int n_in,
                              void* d_out, int out_size, void* d_ws, size_t ws_size,
                              hipStream_t stream) {
    const float* src = (const float*)d_in[0];   // binMapsrc [8,1,320,1024] f32
    const float* dst = (const float*)d_in[1];   // binMapdst
    const float* xx  = (const float*)d_in[2];   // 105, distance-sorted
    const float* yy  = (const float*)d_in[3];   // 105
    // d_in[4..7] (sxx,syy,cxx,cyy) semantics are hardcoded (fixed module consts)
    float* out = (float*)d_out;

    int*      cnt   = (int*)d_ws;
    unsigned* lists = (unsigned*)((char*)d_ws + LISTS_OFF);

    int cap = CAP_MAX;
    size_t need = (size_t)LISTS_OFF + (size_t)N_TILES * cap * sizeof(unsigned);
    if (ws_size < need) {
        long avail = ((long)ws_size - LISTS_OFF) / ((long)N_TILES * 4);
        cap = avail < 1 ? 1 : (avail > CAP_MAX ? CAP_MAX : (int)avail);
    }

    zero_counters<<<(N_TILES + 255) / 256, 256, 0, stream>>>(cnt);

    dim3 g1(WW / 256, HH, BB);   // (4, 320, 8)
    build_points<<<g1, 256, 0, stream>>>(src, dst, xx, yy, out, cnt, lists, cap);

    dim3 g2(TILES_X, TILES_Y, BB);  // (32, 10, 8)
    splat_finalize<<<g2, 256, 0, stream>>>(cnt, lists, out, cap);
}

// Round 2
// 207.321 us; speedup vs baseline: 1.4840x; 1.4840x over previous
//
#include <hip/hip_runtime.h>

// BNMorph forward, sparse-scatter + bitmask-search formulation.
// B=8, H=320, W=1024. Outputs (concat, f32, each [B,H,W]):
//   0 morphedx, 1 morphedy, 2 orgpts_x, 3 orgpts_y, 4 correspts_x, 5 correspts_y

#define BB 8
#define HH 320
#define WW 1024
#define N_PIX (BB*HH*WW)            // 2,621,440
#define WORDS_PER_IMG (HH*(WW/32))  // 10240
#define RR 20
#define TILE 32
#define TILES_X (WW/TILE)           // 32
#define TILES_Y (HH/TILE)           // 10
#define TILES_PER_B (TILES_X*TILES_Y)
#define N_TILES (BB*TILES_PER_B)    // 2560
#define NQ 105
#define CAP_MAX 512
// d_ws layout: [0,16384) cnt | [16384, +655360) packed maps | lists
#define PACK_OFF 16384
#define LISTS_OFF (PACK_OFF + 2*BB*WORDS_PER_IMG*4)   // 671744

// padded transposed weight table: rows = udy 0..41 (41 = zero row),
// cols = udx -4..52 stored at [4+udx], data at cols 4..44, zeros elsewhere
#define WROW 57
#define WROWS 42

typedef unsigned long long u64;

// ---- kernel 1: pack both maps to bitmasks + zero tile counters ----
__global__ __launch_bounds__(256) void pack_zero(
    const float* __restrict__ src, const float* __restrict__ dst,
    unsigned* __restrict__ packed, int* __restrict__ cnt)
{
    int i = blockIdx.x * 256 + threadIdx.x;     // [0, 2*N_PIX)
    if (i < N_TILES) cnt[i] = 0;
    float v = (i < N_PIX) ? src[i] : dst[i - N_PIX];   // wave-uniform branch
    u64 m = __ballot(v > 0.5f);
    if ((threadIdx.x & 31) == 0) {
        unsigned w32 = (threadIdx.x & 32) ? (unsigned)(m >> 32) : (unsigned)m;
        packed[i >> 5] = w32;
    }
}

// ---- kernel 2: sparsity filter + first-hit search, all on bitmasks ----
__global__ __launch_bounds__(256) void build_points(
    const unsigned* __restrict__ packed,
    const float* __restrict__ xx, const float* __restrict__ yy,
    float* __restrict__ out, int* __restrict__ cnt,
    unsigned* __restrict__ lists, int cap)
{
    __shared__ unsigned sS[3][12];   // src rows y-2..y, words wb-1..wb+8
    __shared__ unsigned sD[7][12];   // dst rows y-3..y+3
    __shared__ int prank[NQ], sdxv[NQ], sdyv[NQ];

    int t = threadIdx.x;
    int x0 = blockIdx.x << 8;
    int y  = blockIdx.y;
    int b  = blockIdx.z;
    int wb = x0 >> 5;
    const unsigned* psrc = packed + (size_t)b * WORDS_PER_IMG;
    const unsigned* pdst = packed + (size_t)BB * WORDS_PER_IMG + (size_t)b * WORDS_PER_IMG;

    if (t < 30) {
        int r = t / 10, wi = t % 10;
        int y2 = y - 2 + r, wg = wb - 1 + wi;
        unsigned v = 0;
        if (y2 >= 0 && wg >= 0 && wg < 32) v = psrc[(y2 << 5) + wg];
        sS[r][wi] = v;
    } else if (t < 100) {
        int u = t - 30; int r = u / 10, wi = u % 10;
        int y2 = y - 3 + r, wg = wb - 1 + wi;
        unsigned v = 0;
        if (y2 >= 0 && y2 < HH && wg >= 0 && wg < 32) v = pdst[(y2 << 5) + wg];
        sD[r][wi] = v;
    } else if (t >= 128 && t < 128 + NQ) {
        int k = t - 128;
        int dx = (int)xx[k], dy = (int)yy[k];
        sdxv[k] = dx; sdyv[k] = dy;
        prank[(dy + 3) * 15 + (dx + 7)] = k;   // window pos -> priority rank
    }
    __syncthreads();

    int x  = x0 + t;
    int sh = x & 31;
    bool active = (sS[2][(t >> 5) + 1] >> sh) & 1;

    // sparsity: rows y-2,y-1 dx in [-2,2]; row y dx in [-2,-1]
    int j2 = (((x - 2) >> 5) - wb) + 1;   // local word of bit x-2
    int b2 = (x - 2) & 31;
    #define WIN5(rowp) ((unsigned)((((u64)(rowp)[j2] | ((u64)(rowp)[j2+1] << 32)) >> b2) & 31u))
    bool kept = active;
    if (active) {
        unsigned w5a = WIN5(sS[0]);
        unsigned w5b = WIN5(sS[1]);
        unsigned w5c = WIN5(sS[2]) & 3u;
        kept = !(w5a | w5b | w5c);
    }

    int minr = NQ;
    if (kept) {
        int j7 = (((x - 7) >> 5) - wb) + 1;   // local word of bit x-7
        int b7 = (x - 7) & 31;
        #define WIN15(rowp) ((u64)((((u64)(rowp)[j7] | ((u64)(rowp)[j7+1] << 32)) >> b7) & 0x7FFFu))
        u64 lo = WIN15(sD[0]) | (WIN15(sD[1]) << 15) | (WIN15(sD[2]) << 30) | (WIN15(sD[3]) << 45);
        u64 hi = WIN15(sD[4]) | (WIN15(sD[5]) << 15) | (WIN15(sD[6]) << 30);
        while (lo) { int bb2 = __builtin_ctzll(lo); int r = prank[bb2];      if (r < minr) minr = r; lo &= lo - 1; }
        while (hi) { int bb2 = __builtin_ctzll(hi); int r = prank[60 + bb2]; if (r < minr) minr = r; hi &= hi - 1; }
    }
    bool found = minr < NQ;
    int vx = found ? sdxv[minr] : 0;
    int vy = found ? sdyv[minr] : 0;

    float m  = found ? 1.0f : 0.0f;
    float fx = (float)x, fy = (float)y;
    size_t base = (size_t)b * HH * WW + (size_t)y * WW + x;
    out[2 * (size_t)N_PIX + base] = fx * m;
    out[3 * (size_t)N_PIX + base] = fy * m;
    out[4 * (size_t)N_PIX + base] = (fx + (float)vx) * m;
    out[5 * (size_t)N_PIX + base] = (fy + (float)vy) * m;

    if (found) {
        unsigned pk = (unsigned)x | ((unsigned)y << 10)
                    | ((unsigned)(vx + 7) << 19) | ((unsigned)(vy + 3) << 23);
        int txl = x - RR; txl = (txl < 0 ? 0 : txl) >> 5;
        int txh = x + RR; txh = (txh > WW - 1 ? WW - 1 : txh) >> 5;
        int tyl = y - RR; tyl = (tyl < 0 ? 0 : tyl) >> 5;
        int tyh = y + RR; tyh = (tyh > HH - 1 ? HH - 1 : tyh) >> 5;
        for (int ty = tyl; ty <= tyh; ++ty)
            for (int tx = txl; tx <= txh; ++tx) {
                int tile = b * TILES_PER_B + ty * TILES_X + tx;
                int pos = atomicAdd(&cnt[tile], 1);
                if (pos < cap) lists[(size_t)tile * cap + pos] = pk;
            }
    }
}

// ---- kernel 3: gather-splat per 32x32 tile + finalize morphedx/y ----
__global__ __launch_bounds__(256) void splat_finalize(
    const int* __restrict__ cnt, const unsigned* __restrict__ lists,
    float* __restrict__ out, int cap)
{
    __shared__ float wtab[WROWS * WROW];
    __shared__ unsigned pts[CAP_MAX];
    int t = threadIdx.x;

    for (int i = t; i < WROWS * WROW; i += 256) {
        int r = i / WROW, c = i % WROW;
        int udx = c - 4;
        float v = 0.0f;
        if (r <= 40 && udx >= 0 && udx <= 40) {
            int dxv = udx - 20, dyv = r - 20;
            float d = sqrtf((float)(dxv * dxv + dyv * dyv));
            v = 0.7f * expf((-d * 1.9f) / 24.0f);
        }
        wtab[i] = v;
    }

    int tx = blockIdx.x, ty = blockIdx.y, b = blockIdx.z;
    int tile = b * TILES_PER_B + ty * TILES_X + tx;
    int n = cnt[tile]; if (n > cap) n = cap;
    for (int i = t; i < n; i += 256) pts[i] = lists[(size_t)tile * cap + i];
    __syncthreads();

    // thread = 1 row x 4 consecutive cols
    int r  = t >> 3;                  // 0..31
    int x0 = tx * TILE + (t & 7) * 4;
    int y  = ty * TILE + r;

    float a00 = 0, a01 = 0, a02 = 0, a03 = 0;
    float a10 = 0, a11 = 0, a12 = 0, a13 = 0;
    float a20 = 0, a21 = 0, a22 = 0, a23 = 0;

    for (int p = 0; p < n; ++p) {
        unsigned pk = (unsigned)__builtin_amdgcn_readfirstlane((int)pts[p]);
        int px = pk & 1023;
        int py = (pk >> 10) & 511;
        float pvx = (float)((int)((pk >> 19) & 15) - 7);
        float pvy = (float)((int)((pk >> 23) & 7) - 3);

        int dyr = py - y + 20;
        int row = ((unsigned)dyr > 40u) ? 41 : dyr;      // row 41 = zeros
        int basei = px - x0 + 17;                        // ix-3
        int bc = basei < -4 ? -4 : (basei > 41 ? 41 : basei);
        const float* wr = &wtab[row * WROW + 4 + bc];    // [0..48+3] in row
        float w3 = wr[0], w2 = wr[1], w1 = wr[2], w0 = wr[3];
        // col j uses wr[3-j]
        a00 += w0; a10 += w0 * pvx; a20 += w0 * pvy;
        a01 += w1; a11 += w1 * pvx; a21 += w1 * pvy;
        a02 += w2; a12 += w2 * pvx; a22 += w2 * pvy;
        a03 += w3; a13 += w3 * pvx; a23 += w3 * pvy;
    }

    size_t idx = (size_t)b * HH * WW + (size_t)y * WW + x0;
    float d0 = a00 + 1.6f, d1 = a01 + 1.6f, d2 = a02 + 1.6f, d3 = a03 + 1.6f;
    float4 ox = { (float)x0     + a10 / d0, (float)(x0+1) + a11 / d1,
                  (float)(x0+2) + a12 / d2, (float)(x0+3) + a13 / d3 };
    float4 oy = { (float)y + a20 / d0, (float)y + a21 / d1,
                  (float)y + a22 / d2, (float)y + a23 / d3 };
    *reinterpret_cast<float4*>(out + idx)                   = ox;
    *reinterpret_cast<float4*>(out + (size_t)N_PIX + idx)   = oy;
}

extern "C" void kernel_launch(void* const* d_in, const int* in_sizes, int n_in,
                              void* d_out, int out_size, void* d_ws, size_t ws_size,
                              hipStream_t stream) {
    const float* src = (const float*)d_in[0];
    const float* dst = (const float*)d_in[1];
    const float* xx  = (const float*)d_in[2];
    const float* yy  = (const float*)d_in[3];
    float* out = (float*)d_out;

    int*      cnt    = (int*)d_ws;
    unsigned* packed = (unsigned*)((char*)d_ws + PACK_OFF);
    unsigned* lists  = (unsigned*)((char*)d_ws + LISTS_OFF);

    int cap = CAP_MAX;
    size_t need = (size_t)LISTS_OFF + (size_t)N_TILES * cap * sizeof(unsigned);
    if (ws_size < need) {
        long avail = ((long)ws_size - LISTS_OFF) / ((long)N_TILES * 4);
        cap = avail < 1 ? 1 : (avail > CAP_MAX ? CAP_MAX : (int)avail);
    }

    pack_zero<<<(2 * N_PIX) / 256, 256, 0, stream>>>(src, dst, packed, cnt);

    dim3 g1(WW / 256, HH, BB);
    build_points<<<g1, 256, 0, stream>>>(packed, xx, yy, out, cnt, lists, cap);

    dim3 g2(TILES_X, TILES_Y, BB);
    splat_finalize<<<g2, 256, 0, stream>>>(cnt, lists, out, cap);
}

// Round 3
// 184.018 us; speedup vs baseline: 1.6720x; 1.1266x over previous
//
#include <hip/hip_runtime.h>

// BNMorph forward — bit-parallel build + 64x64-tile gather-splat.
// B=8, H=320, W=1024. Outputs (concat, f32, each [B,H,W]):
//   0 morphedx, 1 morphedy, 2 orgpts_x, 3 orgpts_y, 4 correspts_x, 5 correspts_y

#define BB 8
#define HH 320
#define WW 1024
#define N_PIX (BB*HH*WW)            // 2,621,440
#define WPI (HH*(WW/32))            // words per image = 10240
#define RR 20
#define TILE 64
#define TX_N (WW/TILE)              // 16
#define TY_N (HH/TILE)              // 5
#define TPB (TX_N*TY_N)             // 80 tiles per image
#define N_TILES (BB*TPB)            // 640
#define NQ 105
#define CAP_MAX 512
#define PACK_OFF 16384
#define LISTS_OFF (PACK_OFF + 2*BB*WPI*4)

#define WROW 57
#define WROWS 42

typedef unsigned long long u64;

// ---- kernel 1: pack both maps to bitmasks + zero tile counters ----
__global__ __launch_bounds__(256) void pack_zero(
    const float* __restrict__ src, const float* __restrict__ dst,
    unsigned* __restrict__ packed, int* __restrict__ cnt)
{
    int i = blockIdx.x * 256 + threadIdx.x;     // [0, 2*N_PIX)
    if (i < N_TILES) cnt[i] = 0;
    float v = (i < N_PIX) ? src[i] : dst[i - N_PIX];   // wave-uniform branch
    u64 m = __ballot(v > 0.5f);
    if ((threadIdx.x & 31) == 0) {
        unsigned w32 = (threadIdx.x & 32) ? (unsigned)(m >> 32) : (unsigned)m;
        packed[i >> 5] = w32;
    }
}

// ---- kernel 2: bit-parallel sparsity + search; coalesced dense writes ----
// block = 256 threads = 8 rows x 32 words (8 x 1024 px). grid (40, 8).
__global__ __launch_bounds__(256) void build_points(
    const unsigned* __restrict__ packed,
    const float* __restrict__ xx, const float* __restrict__ yy,
    float* __restrict__ out, int* __restrict__ cnt,
    unsigned* __restrict__ lists, int cap)
{
    __shared__ unsigned sS[10][32];    // src rows y0-2 .. y0+7
    __shared__ unsigned sD[14][32];    // dst rows y0-3 .. y0+10
    __shared__ unsigned sMask[8][32];  // found mask per word
    __shared__ unsigned sVB[8][256];   // vx/vy byte per pixel (u32-packed)
    __shared__ int prank[NQ], sdxv[NQ], sdyv[NQ];

    int t  = threadIdx.x;
    int y0 = blockIdx.x * 8;
    int b  = blockIdx.y;
    const unsigned* psrc = packed + (size_t)b * WPI;
    const unsigned* pdst = packed + (size_t)(BB + b) * WPI;

    for (int i = t; i < 320; i += 256) {
        int r = i >> 5, w = i & 31;
        int y2 = y0 - 2 + r;
        sS[r][w] = (y2 >= 0) ? psrc[(y2 << 5) + w] : 0u;   // y2<=y0+7<320
    }
    for (int i = t; i < 448; i += 256) {
        int r = i >> 5, w = i & 31;
        int y2 = y0 - 3 + r;
        sD[r][w] = (y2 >= 0 && y2 < HH) ? pdst[(y2 << 5) + w] : 0u;
    }
    if (t < NQ) {
        int dx = (int)xx[t], dy = (int)yy[t];
        sdxv[t] = dx; sdyv[t] = dy;
        prank[(dy + 3) * 15 + (dx + 7)] = t;
    }
    __syncthreads();

    int r = t >> 5, w = t & 31;
    int y = y0 + r;

    unsigned C = sS[r + 2][w];
    unsigned kept = 0;
    if (C) {
        // ext36: bits x0-2 .. x0+33 of a row
        #define EXT5(row) ( (u64)((w ? (row)[w-1] : 0u) >> 30) \
                          | ((u64)(row)[w] << 2) \
                          | ((u64)((w < 31 ? (row)[w+1] : 0u) & 3u) << 34) )
        u64 a = EXT5(sS[r]) | EXT5(sS[r + 1]);              // rows y-2,y-1
        u64 or5 = a | (a >> 1) | (a >> 2) | (a >> 3) | (a >> 4);
        u64 e2 = EXT5(sS[r + 2]);                           // row y, dx=-2,-1
        u64 or2 = e2 | (e2 >> 1);
        kept = C & ~(unsigned)(or5 | or2);
    }

    unsigned found = 0;
    if (kept) {
        // ext46: bits x0-7 .. x0+38; OR rows then dilate 15 wide
        u64 dil = 0;
        #pragma unroll
        for (int rr = 0; rr < 7; ++rr) {
            const unsigned* row = sD[r + rr];               // dst row y-3+rr
            unsigned L = w ? row[w-1] : 0u;
            unsigned R = (w < 31) ? row[w+1] : 0u;
            dil |= (u64)(L >> 25) | ((u64)row[w] << 7) | ((u64)(R & 0x7Fu) << 39);
        }
        u64 a2 = dil | (dil >> 1);
        u64 b2 = a2 | (a2 >> 2);
        u64 c2 = b2 | (b2 >> 4);
        u64 o15 = c2 | (c2 >> 7);
        found = kept & (unsigned)o15;
    }
    sMask[r][w] = found;

    unsigned fiter = found;
    while (fiter) {
        int bit = __builtin_ctz(fiter); fiter &= fiter - 1;
        int x = (w << 5) + bit;
        int x7 = x - 7;
        int j = x7 >> 5;            // -1..31
        int sh = x7 & 31;
        u64 lo = 0, hi = 0;
        #pragma unroll
        for (int rr = 0; rr < 7; ++rr) {
            const unsigned* row = sD[r + rr];
            unsigned W0 = (j >= 0) ? row[j] : 0u;
            unsigned W1 = (j + 1 < 32) ? row[j + 1] : 0u;
            u64 win = (((u64)W0 | ((u64)W1 << 32)) >> sh) & 0x7FFFull;
            if (rr < 4) lo |= win << (15 * rr);
            else        hi |= win << (15 * (rr - 4));
        }
        int minr = NQ;
        while (lo) { int bb2 = __builtin_ctzll(lo); lo &= lo - 1; int rk = prank[bb2];      if (rk < minr) minr = rk; }
        while (hi) { int bb2 = __builtin_ctzll(hi); hi &= hi - 1; int rk = prank[60 + bb2]; if (rk < minr) minr = rk; }
        int vx = sdxv[minr], vy = sdyv[minr];

        ((unsigned char*)sVB)[(r << 10) + x] =
            (unsigned char)((vx + 7) | ((vy + 3) << 4));

        unsigned pk = (unsigned)x | ((unsigned)y << 10)
                    | ((unsigned)(vx + 7) << 19) | ((unsigned)(vy + 3) << 23);
        int txl = x - RR; txl = (txl < 0 ? 0 : txl) >> 6;
        int txh = x + RR; txh = (txh > WW - 1 ? WW - 1 : txh) >> 6;
        int tyl = y - RR; tyl = (tyl < 0 ? 0 : tyl) >> 6;
        int tyh = y + RR; tyh = (tyh > HH - 1 ? HH - 1 : tyh) >> 6;
        for (int ty = tyl; ty <= tyh; ++ty)
            for (int tx = txl; tx <= txh; ++tx) {
                int tile = b * TPB + ty * TX_N + tx;
                int pos = atomicAdd(&cnt[tile], 1);
                if (pos < cap) lists[(size_t)tile * cap + pos] = pk;
            }
    }
    __syncthreads();

    // store phase: thread t writes 4 px per row, fully coalesced float4
    int xs = t << 2;
    int wq = xs >> 5, bo = xs & 31;
    size_t bbase = (size_t)b * HH * WW;
    #pragma unroll
    for (int g = 0; g < 8; ++g) {
        unsigned mw = sMask[g][wq];
        unsigned vb = sVB[g][t];
        float fy = (float)(y0 + g);
        float4 o2, o3, o4, o5;
        float* po2 = &o2.x; float* po3 = &o3.x; float* po4 = &o4.x; float* po5 = &o5.x;
        #pragma unroll
        for (int jj = 0; jj < 4; ++jj) {
            float fm = (float)((mw >> (bo + jj)) & 1u);
            unsigned by = (vb >> (8 * jj)) & 255u;
            float fvx = (float)((int)(by & 15u) - 7);
            float fvy = (float)((int)(by >> 4) - 3);
            float fx = (float)(xs + jj);
            po2[jj] = fx * fm;
            po3[jj] = fy * fm;
            po4[jj] = (fx + fvx) * fm;
            po5[jj] = (fy + fvy) * fm;
        }
        size_t idx = bbase + (size_t)(y0 + g) * WW + xs;
        *reinterpret_cast<float4*>(out + 2 * (size_t)N_PIX + idx) = o2;
        *reinterpret_cast<float4*>(out + 3 * (size_t)N_PIX + idx) = o3;
        *reinterpret_cast<float4*>(out + 4 * (size_t)N_PIX + idx) = o4;
        *reinterpret_cast<float4*>(out + 5 * (size_t)N_PIX + idx) = o5;
    }
}

// ---- kernel 3: 64x64-tile gather-splat, 4x4 px/thread ----
__global__ __launch_bounds__(256) void splat_finalize(
    const int* __restrict__ cnt, const unsigned* __restrict__ lists,
    float* __restrict__ out, int cap)
{
    __shared__ float wtab[WROWS * WROW];
    __shared__ unsigned pts[CAP_MAX];
    int t = threadIdx.x;

    for (int i = t; i < WROWS * WROW; i += 256) {
        int r = i / WROW, c = i % WROW;
        int udx = c - 4;
        float v = 0.0f;
        if (r <= 40 && udx >= 0 && udx <= 40) {
            int dxv = udx - 20, dyv = r - 20;
            float d = sqrtf((float)(dxv * dxv + dyv * dyv));
            v = 0.7f * expf((-d * 1.9f) / 24.0f);
        }
        wtab[i] = v;
    }

    int txT = blockIdx.x, tyT = blockIdx.y, b = blockIdx.z;
    int tile = b * TPB + tyT * TX_N + txT;
    int n = cnt[tile]; if (n > cap) n = cap;
    for (int i = t; i < n; i += 256) pts[i] = lists[(size_t)tile * cap + i];
    __syncthreads();

    int x0  = txT * TILE + (t & 15) * 4;
    int y0t = tyT * TILE + (t >> 4) * 4;
    int wy0 = tyT * TILE + (t >> 6) * 16;   // wave-uniform strip top row

    float a0[4][4] = {}, a1[4][4] = {}, a2[4][4] = {};

    for (int p = 0; p < n; ++p) {
        int spk = __builtin_amdgcn_readfirstlane((int)pts[p]);
        int py = (spk >> 10) & 511;
        if (py < wy0 - 20 || py > wy0 + 35) continue;    // wave-uniform skip
        int px = spk & 1023;
        float pvx = (float)(((spk >> 19) & 15) - 7);
        float pvy = (float)(((spk >> 23) & 7) - 3);

        int basei = px - x0 + 17;
        int bc = basei < -4 ? -4 : (basei > 41 ? 41 : basei);
        int coff = 4 + bc;
        #pragma unroll
        for (int ry = 0; ry < 4; ++ry) {
            int dyr = py - (y0t + ry) + 20;
            int rowi = ((unsigned)dyr > 40u) ? 41 : dyr;  // row 41 = zeros
            const float* wr = &wtab[rowi * WROW + coff];
            float w3 = wr[0], w2 = wr[1], w1 = wr[2], w0 = wr[3];
            a0[ry][0] += w0; a1[ry][0] += w0 * pvx; a2[ry][0] += w0 * pvy;
            a0[ry][1] += w1; a1[ry][1] += w1 * pvx; a2[ry][1] += w1 * pvy;
            a0[ry][2] += w2; a1[ry][2] += w2 * pvx; a2[ry][2] += w2 * pvy;
            a0[ry][3] += w3; a1[ry][3] += w3 * pvx; a2[ry][3] += w3 * pvy;
        }
    }

    size_t bbase = (size_t)b * HH * WW;
    #pragma unroll
    for (int ry = 0; ry < 4; ++ry) {
        int y = y0t + ry;
        size_t idx = bbase + (size_t)y * WW + x0;
        float d0 = a0[ry][0] + 1.6f, d1 = a0[ry][1] + 1.6f;
        float d2 = a0[ry][2] + 1.6f, d3 = a0[ry][3] + 1.6f;
        float4 ox = { (float)x0     + a1[ry][0] / d0, (float)(x0+1) + a1[ry][1] / d1,
                      (float)(x0+2) + a1[ry][2] / d2, (float)(x0+3) + a1[ry][3] / d3 };
        float4 oy = { (float)y + a2[ry][0] / d0, (float)y + a2[ry][1] / d1,
                      (float)y + a2[ry][2] / d2, (float)y + a2[ry][3] / d3 };
        *reinterpret_cast<float4*>(out + idx)                 = ox;
        *reinterpret_cast<float4*>(out + (size_t)N_PIX + idx) = oy;
    }
}

extern "C" void kernel_launch(void* const* d_in, const int* in_sizes, int n_in,
                              void* d_out, int out_size, void* d_ws, size_t ws_size,
                              hipStream_t stream) {
    const float* src = (const float*)d_in[0];
    const float* dst = (const float*)d_in[1];
    const float* xx  = (const float*)d_in[2];
    const float* yy  = (const float*)d_in[3];
    float* out = (float*)d_out;

    int*      cnt    = (int*)d_ws;
    unsigned* packed = (unsigned*)((char*)d_ws + PACK_OFF);
    unsigned* lists  = (unsigned*)((char*)d_ws + LISTS_OFF);

    int cap = CAP_MAX;
    size_t need = (size_t)LISTS_OFF + (size_t)N_TILES * cap * sizeof(unsigned);
    if (ws_size < need) {
        long avail = ((long)ws_size - LISTS_OFF) / ((long)N_TILES * 4);
        cap = avail < 1 ? 1 : (avail > CAP_MAX ? CAP_MAX : (int)avail);
    }

    pack_zero<<<(2 * N_PIX) / 256, 256, 0, stream>>>(src, dst, packed, cnt);

    dim3 g1(HH / 8, BB);
    build_points<<<g1, 256, 0, stream>>>(packed, xx, yy, out, cnt, lists, cap);

    dim3 g2(TX_N, TY_N, BB);
    splat_finalize<<<g2, 256, 0, stream>>>(cnt, lists, out, cap);
}

// Round 4
// 169.201 us; speedup vs baseline: 1.8184x; 1.0876x over previous
//
#include <hip/hip_runtime.h>

// BNMorph forward — bit-parallel build + rotated-table gather-splat (64x32 tiles).
// B=8, H=320, W=1024. Outputs (concat, f32, each [B,H,W]):
//   0 morphedx, 1 morphedy, 2 orgpts_x, 3 orgpts_y, 4 correspts_x, 5 correspts_y

#define BB 8
#define HH 320
#define WW 1024
#define N_PIX (BB*HH*WW)            // 2,621,440
#define WPI (HH*(WW/32))            // 10240 words per image
#define RR 20
#define TLW 64
#define TLH 32
#define TXN (WW/TLW)                // 16
#define TYN (HH/TLH)                // 10
#define TPB (TXN*TYN)               // 160
#define N_TILES (BB*TPB)            // 1280
#define NQ 105
#define CAP_MAX 512
#define PACK_OFF 16384
#define LISTS_OFF (PACK_OFF + 2*BB*WPI*4)   // 671744

#define WCOPY 48                    // floats per row per rotated copy
#define WROWS 42                    // rows 0..40 data, 41 = zeros
#define WTABN (4*WROWS*WCOPY)       // 8064 floats

typedef unsigned long long u64;

// ---- kernel 1: pack both maps to bitmasks (float4 + shfl-OR) + zero counters ----
__global__ __launch_bounds__(256) void pack_zero(
    const float* __restrict__ src, const float* __restrict__ dst,
    unsigned* __restrict__ packed, int* __restrict__ cnt)
{
    int t = threadIdx.x;
    int i = blockIdx.x * 256 + t;           // float4 index in [0, 2*N_PIX/4)
    if (i < N_TILES) cnt[i] = 0;
    const float4* p = (i < (N_PIX >> 2)) ? (const float4*)src + i
                                         : (const float4*)dst + (i - (N_PIX >> 2));
    float4 v = *p;
    unsigned nib = (v.x > 0.5f ? 1u : 0u) | (v.y > 0.5f ? 2u : 0u)
                 | (v.z > 0.5f ? 4u : 0u) | (v.w > 0.5f ? 8u : 0u);
    unsigned val = nib << ((t & 7) * 4);
    val |= __shfl_xor(val, 1);
    val |= __shfl_xor(val, 2);
    val |= __shfl_xor(val, 4);
    if ((t & 7) == 0) packed[i >> 3] = val;
}

// ---- kernel 2: bit-parallel sparsity + search, 4 rows/block ----
// block = 256 threads (128 compute lanes = 4 rows x 32 words). grid (80, 8).
__global__ __launch_bounds__(256) void build_points(
    const unsigned* __restrict__ packed,
    const float* __restrict__ xx, const float* __restrict__ yy,
    float* __restrict__ out, int* __restrict__ cnt,
    unsigned* __restrict__ lists, int cap)
{
    __shared__ unsigned sS[6][32];     // src rows y0-2 .. y0+3
    __shared__ unsigned sD[10][32];    // dst rows y0-3 .. y0+6
    __shared__ unsigned sMask[4][32];
    __shared__ unsigned sVB[4][256];   // vx/vy byte per pixel
    __shared__ int prank[NQ], sdxv[NQ], sdyv[NQ];

    int t  = threadIdx.x;
    int y0 = blockIdx.x * 4;
    int b  = blockIdx.y;
    const unsigned* psrc = packed + (size_t)b * WPI;
    const unsigned* pdst = packed + (size_t)(BB + b) * WPI;

    if (t < 192) {
        int r = t >> 5, w = t & 31;
        int y2 = y0 - 2 + r;
        sS[r][w] = (y2 >= 0 && y2 < HH) ? psrc[(y2 << 5) + w] : 0u;
    }
    for (int i = t; i < 320; i += 256) {
        int r = i >> 5, w = i & 31;
        int y2 = y0 - 3 + r;
        sD[r][w] = (y2 >= 0 && y2 < HH) ? pdst[(y2 << 5) + w] : 0u;
    }
    if (t < NQ) {
        int dx = (int)xx[t], dy = (int)yy[t];
        sdxv[t] = dx; sdyv[t] = dy;
        prank[(dy + 3) * 15 + (dx + 7)] = t;
    }
    __syncthreads();

    if (t < 128) {
        int r = t >> 5, w = t & 31;
        int y = y0 + r;

        unsigned C = sS[r + 2][w];
        unsigned kept = 0;
        if (C) {
            #define EXT5(row) ( (u64)((w ? (row)[w-1] : 0u) >> 30) \
                              | ((u64)(row)[w] << 2) \
                              | ((u64)((w < 31 ? (row)[w+1] : 0u) & 3u) << 34) )
            u64 a = EXT5(sS[r]) | EXT5(sS[r + 1]);
            u64 or5 = a | (a >> 1) | (a >> 2) | (a >> 3) | (a >> 4);
            u64 e2 = EXT5(sS[r + 2]);
            u64 or2 = e2 | (e2 >> 1);
            kept = C & ~(unsigned)(or5 | or2);
        }

        unsigned found = 0;
        if (kept) {
            u64 dil = 0;
            #pragma unroll
            for (int rr = 0; rr < 7; ++rr) {
                const unsigned* row = sD[r + rr];
                unsigned L = w ? row[w-1] : 0u;
                unsigned R = (w < 31) ? row[w+1] : 0u;
                dil |= (u64)(L >> 25) | ((u64)row[w] << 7) | ((u64)(R & 0x7Fu) << 39);
            }
            u64 a2 = dil | (dil >> 1);
            u64 b2 = a2 | (a2 >> 2);
            u64 c2 = b2 | (b2 >> 4);
            u64 o15 = c2 | (c2 >> 7);
            found = kept & (unsigned)o15;
        }
        sMask[r][w] = found;

        unsigned fiter = found;
        while (fiter) {
            int bit = __builtin_ctz(fiter); fiter &= fiter - 1;
            int x = (w << 5) + bit;
            int x7 = x - 7;
            int j = x7 >> 5;
            int sh = x7 & 31;
            u64 lo = 0, hi = 0;
            #pragma unroll
            for (int rr = 0; rr < 7; ++rr) {
                const unsigned* row = sD[r + rr];
                unsigned W0 = (j >= 0) ? row[j] : 0u;
                unsigned W1 = (j + 1 < 32) ? row[j + 1] : 0u;
                u64 win = (((u64)W0 | ((u64)W1 << 32)) >> sh) & 0x7FFFull;
                if (rr < 4) lo |= win << (15 * rr);
                else        hi |= win << (15 * (rr - 4));
            }
            int minr = NQ;
            while (lo) { int bb2 = __builtin_ctzll(lo); lo &= lo - 1; int rk = prank[bb2];      if (rk < minr) minr = rk; }
            while (hi) { int bb2 = __builtin_ctzll(hi); hi &= hi - 1; int rk = prank[60 + bb2]; if (rk < minr) minr = rk; }
            int vx = sdxv[minr], vy = sdyv[minr];

            ((unsigned char*)sVB)[(r << 10) + x] =
                (unsigned char)((vx + 7) | ((vy + 3) << 4));

            unsigned pk = (unsigned)x | ((unsigned)y << 10)
                        | ((unsigned)(vx + 7) << 19) | ((unsigned)(vy + 3) << 23);
            int txl = x - RR; txl = (txl < 0 ? 0 : txl) >> 6;
            int txh = x + RR; txh = (txh > WW - 1 ? WW - 1 : txh) >> 6;
            int tyl = y - RR; tyl = (tyl < 0 ? 0 : tyl) >> 5;
            int tyh = y + RR; tyh = (tyh > HH - 1 ? HH - 1 : tyh) >> 5;
            for (int ty = tyl; ty <= tyh; ++ty)
                for (int tx = txl; tx <= txh; ++tx) {
                    int tile = b * TPB + ty * TXN + tx;
                    int pos = atomicAdd(&cnt[tile], 1);
                    if (pos < cap) lists[(size_t)tile * cap + pos] = pk;
                }
        }
    }
    __syncthreads();

    // store phase: thread t covers px 4t..4t+3 of each of the 4 rows
    int xs = t << 2;
    int wq = t >> 3;
    int bo = xs & 31;
    size_t bbase = (size_t)b * HH * WW;
    #pragma unroll
    for (int g = 0; g < 4; ++g) {
        unsigned mw = sMask[g][wq];
        unsigned vb = sVB[g][t];
        float fy = (float)(y0 + g);
        float4 o2, o3, o4, o5;
        float* po2 = &o2.x; float* po3 = &o3.x; float* po4 = &o4.x; float* po5 = &o5.x;
        #pragma unroll
        for (int jj = 0; jj < 4; ++jj) {
            float fm = (float)((mw >> (bo + jj)) & 1u);
            unsigned by = (vb >> (8 * jj)) & 255u;
            float fvx = (float)((int)(by & 15u) - 7);
            float fvy = (float)((int)(by >> 4) - 3);
            float fx = (float)(xs + jj);
            po2[jj] = fx * fm;
            po3[jj] = fy * fm;
            po4[jj] = (fx + fvx) * fm;
            po5[jj] = (fy + fvy) * fm;
        }
        size_t idx = bbase + (size_t)(y0 + g) * WW + xs;
        *reinterpret_cast<float4*>(out + 2 * (size_t)N_PIX + idx) = o2;
        *reinterpret_cast<float4*>(out + 3 * (size_t)N_PIX + idx) = o3;
        *reinterpret_cast<float4*>(out + 4 * (size_t)N_PIX + idx) = o4;
        *reinterpret_cast<float4*>(out + 5 * (size_t)N_PIX + idx) = o5;
    }
}

// ---- kernel 3: 64x32-tile gather-splat; rotated table, b128 weights ----
__global__ __launch_bounds__(256) void splat_finalize(
    const int* __restrict__ cnt, const unsigned* __restrict__ lists,
    float* __restrict__ out, int cap)
{
    __shared__ __align__(16) float wtab[WTABN];
    __shared__ __align__(16) unsigned pts[CAP_MAX];
    int t = threadIdx.x;

    for (int i = t; i < WTABN; i += 256) {
        int rot = i / (WROWS * WCOPY);
        int rem = i - rot * (WROWS * WCOPY);
        int row = rem / WCOPY;
        int c   = rem - row * WCOPY;
        int pc  = c + rot;                 // padded-row index 0..50
        float v = 0.0f;
        if (row <= 40 && pc >= 4 && pc <= 44) {
            int dxv = pc - 24, dyv = row - 20;
            float d = sqrtf((float)(dxv * dxv + dyv * dyv));
            v = 0.7f * expf((-d * 1.9f) / 24.0f);
        }
        wtab[i] = v;
    }

    int txT = blockIdx.x, tyT = blockIdx.y, b = blockIdx.z;
    int tile = b * TPB + tyT * TXN + txT;
    int n = cnt[tile]; if (n > cap) n = cap;
    for (int i = t; i < n; i += 256) pts[i] = lists[(size_t)tile * cap + i];
    __syncthreads();

    int x0  = txT * TLW + (t & 15) * 4;
    int y0t = tyT * TLH + (t >> 4) * 2;     // thread rows y0t, y0t+1
    int wy0 = tyT * TLH + (t >> 6) * 8;     // wave strip rows [wy0, wy0+7]

    float a0[2][4] = {}, a1[2][4] = {}, a2[2][4] = {};

    for (int p = 0; p < n; p += 4) {
        uint4 P = *(const uint4*)&pts[p];    // broadcast batch of 4 points
        #pragma unroll
        for (int k = 0; k < 4; ++k) {
            if (p + k >= n) break;
            int spk = __builtin_amdgcn_readfirstlane(
                (int)(k == 0 ? P.x : k == 1 ? P.y : k == 2 ? P.z : P.w));
            int py = (spk >> 10) & 511;
            if (py < wy0 - 20 || py > wy0 + 27) continue;   // wave-uniform skip
            int px = spk & 1023;
            float pvx = (float)(((spk >> 19) & 15) - 7);
            float pvy = (float)(((spk >> 23) & 7) - 3);

            int coff = px - x0 + 21;                        // col3's padded idx
            coff = coff < 0 ? 0 : (coff > 45 ? 45 : coff);  // clamp -> zero pads
            int rot = coff & 3;
            int cb  = rot * (WROWS * WCOPY) + (coff & ~3);
            #pragma unroll
            for (int ry = 0; ry < 2; ++ry) {
                int dyr = py - (y0t + ry) + 20;
                int rowi = ((unsigned)dyr > 40u) ? 41 : dyr;  // row 41 = zeros
                float4 wv = *(const float4*)&wtab[cb + rowi * WCOPY];
                // col j uses element (3-j): padded idx coff+3-j
                a0[ry][0] += wv.w; a1[ry][0] += wv.w * pvx; a2[ry][0] += wv.w * pvy;
                a0[ry][1] += wv.z; a1[ry][1] += wv.z * pvx; a2[ry][1] += wv.z * pvy;
                a0[ry][2] += wv.y; a1[ry][2] += wv.y * pvx; a2[ry][2] += wv.y * pvy;
                a0[ry][3] += wv.x; a1[ry][3] += wv.x * pvx; a2[ry][3] += wv.x * pvy;
            }
        }
    }

    size_t bbase = (size_t)b * HH * WW;
    #pragma unroll
    for (int ry = 0; ry < 2; ++ry) {
        int y = y0t + ry;
        size_t idx = bbase + (size_t)y * WW + x0;
        float d0 = a0[ry][0] + 1.6f, d1 = a0[ry][1] + 1.6f;
        float d2 = a0[ry][2] + 1.6f, d3 = a0[ry][3] + 1.6f;
        float4 ox = { (float)x0     + a1[ry][0] / d0, (float)(x0+1) + a1[ry][1] / d1,
                      (float)(x0+2) + a1[ry][2] / d2, (float)(x0+3) + a1[ry][3] / d3 };
        float4 oy = { (float)y + a2[ry][0] / d0, (float)y + a2[ry][1] / d1,
                      (float)y + a2[ry][2] / d2, (float)y + a2[ry][3] / d3 };
        *reinterpret_cast<float4*>(out + idx)                 = ox;
        *reinterpret_cast<float4*>(out + (size_t)N_PIX + idx) = oy;
    }
}

extern "C" void kernel_launch(void* const* d_in, const int* in_sizes, int n_in,
                              void* d_out, int out_size, void* d_ws, size_t ws_size,
                              hipStream_t stream) {
    const float* src = (const float*)d_in[0];
    const float* dst = (const float*)d_in[1];
    const float* xx  = (const float*)d_in[2];
    const float* yy  = (const float*)d_in[3];
    float* out = (float*)d_out;

    int*      cnt    = (int*)d_ws;
    unsigned* packed = (unsigned*)((char*)d_ws + PACK_OFF);
    unsigned* lists  = (unsigned*)((char*)d_ws + LISTS_OFF);

    int cap = CAP_MAX;
    size_t need = (size_t)LISTS_OFF + (size_t)N_TILES * cap * sizeof(unsigned);
    if (ws_size < need) {
        long avail = ((long)ws_size - LISTS_OFF) / ((long)N_TILES * 4);
        cap = avail < 1 ? 1 : (avail > CAP_MAX ? CAP_MAX : (int)avail);
    }

    pack_zero<<<(2 * N_PIX / 4) / 256, 256, 0, stream>>>(src, dst, packed, cnt);

    dim3 g1(HH / 4, BB);
    build_points<<<g1, 256, 0, stream>>>(packed, xx, yy, out, cnt, lists, cap);

    dim3 g2(TXN, TYN, BB);
    splat_finalize<<<g2, 256, 0, stream>>>(cnt, lists, out, cap);
}

// Round 5
// 149.876 us; speedup vs baseline: 2.0528x; 1.1289x over previous
//
#include <hip/hip_runtime.h>

// BNMorph forward — phase-parallel build + pk-f32 gather-splat (64x32 tiles).
// B=8, H=320, W=1024. Outputs (concat, f32, each [B,H,W]):
//   0 morphedx, 1 morphedy, 2 orgpts_x, 3 orgpts_y, 4 correspts_x, 5 correspts_y

#define BB 8
#define HH 320
#define WW 1024
#define N_PIX (BB*HH*WW)            // 2,621,440
#define WPI (HH*(WW/32))            // 10240 words per image
#define RR 20
#define TLW 64
#define TLH 32
#define TXN (WW/TLW)                // 16
#define TYN (HH/TLH)                // 10
#define TPB (TXN*TYN)               // 160
#define N_TILES (BB*TPB)            // 1280
#define NQ 105
#define CAP_MAX 512
#define PACK_OFF 16384
#define WTABN (4*42*48)             // 8064 floats
#define WTAB_OFF (PACK_OFF + 2*BB*WPI*4)     // 671744 (16B aligned)
#define LISTS_OFF (WTAB_OFF + WTABN*4)       // 704000 (16B aligned)

typedef unsigned long long u64;
typedef float v2f __attribute__((ext_vector_type(2)));

// ---- kernel 1: pack maps to bitmasks + zero counters + build weight table ----
__global__ __launch_bounds__(256) void pack_zero(
    const float* __restrict__ src, const float* __restrict__ dst,
    unsigned* __restrict__ packed, int* __restrict__ cnt,
    float* __restrict__ wtab_g)
{
    int t = threadIdx.x;
    int i = blockIdx.x * 256 + t;           // float4 index in [0, 2*N_PIX/4)
    if (i < N_TILES) cnt[i] = 0;
    if (i < WTABN) {                        // rotated-padded weight table
        int rot = i / (42 * 48);
        int rem = i - rot * (42 * 48);
        int row = rem / 48, c = rem - row * 48;
        int pc = c + rot;
        float v = 0.0f;
        if (row <= 40 && pc >= 4 && pc <= 44) {
            int dxv = pc - 24, dyv = row - 20;
            float d = sqrtf((float)(dxv * dxv + dyv * dyv));
            v = 0.7f * expf((-d * 1.9f) / 24.0f);
        }
        wtab_g[i] = v;
    }
    const float4* p = (i < (N_PIX >> 2)) ? (const float4*)src + i
                                         : (const float4*)dst + (i - (N_PIX >> 2));
    float4 v = *p;
    unsigned nib = (v.x > 0.5f ? 1u : 0u) | (v.y > 0.5f ? 2u : 0u)
                 | (v.z > 0.5f ? 4u : 0u) | (v.w > 0.5f ? 8u : 0u);
    unsigned val = nib << ((t & 7) * 4);
    val |= __shfl_xor(val, 1);
    val |= __shfl_xor(val, 2);
    val |= __shfl_xor(val, 4);
    if ((t & 7) == 0) packed[i >> 3] = val;
}

// ---- kernel 2: phase-parallel sparsity + search, 4 rows/block, grid (80,8) ----
__global__ __launch_bounds__(256) void build_points(
    const unsigned* __restrict__ packed,
    const float* __restrict__ xx, const float* __restrict__ yy,
    float* __restrict__ out, int* __restrict__ cnt,
    unsigned* __restrict__ lists, int cap)
{
    __shared__ unsigned sS[6][32];     // src rows y0-2 .. y0+3
    __shared__ unsigned sD[10][32];    // dst rows y0-3 .. y0+6
    __shared__ unsigned sMask[4][32];
    __shared__ unsigned sVB[4][256];   // vx/vy byte per pixel
    __shared__ unsigned sPtXY[256];    // compacted found px: (r<<10)|x
    __shared__ unsigned sPk[256];      // packed point records
    __shared__ unsigned sPairs[1024];  // (ptIdx<<16)|tile
    __shared__ int prank[NQ], sdxv[NQ], sdyv[NQ];
    __shared__ int lcnt[2];            // [0]=nPts [1]=nPairs

    int t  = threadIdx.x;
    int y0 = blockIdx.x * 4;
    int b  = blockIdx.y;
    const unsigned* psrc = packed + (size_t)b * WPI;
    const unsigned* pdst = packed + (size_t)(BB + b) * WPI;

    if (t < 192) {
        int r = t >> 5, w = t & 31;
        int y2 = y0 - 2 + r;
        sS[r][w] = (y2 >= 0 && y2 < HH) ? psrc[(y2 << 5) + w] : 0u;
    }
    for (int i = t; i < 320; i += 256) {
        int r = i >> 5, w = i & 31;
        int y2 = y0 - 3 + r;
        sD[r][w] = (y2 >= 0 && y2 < HH) ? pdst[(y2 << 5) + w] : 0u;
    }
    if (t < NQ) {
        int dx = (int)xx[t], dy = (int)yy[t];
        sdxv[t] = dx; sdyv[t] = dy;
        prank[(dy + 3) * 15 + (dx + 7)] = t;
    }
    if (t < 2) lcnt[t] = 0;
    #pragma unroll
    for (int g = 0; g < 4; ++g) sVB[g][t] = 0;
    __syncthreads();

    // P1: bit-parallel kept/found masks + compaction
    if (t < 128) {
        int r = t >> 5, w = t & 31;
        unsigned C = sS[r + 2][w];
        unsigned kept = 0;
        if (C) {
            #define EXT5(row) ( (u64)((w ? (row)[w-1] : 0u) >> 30) \
                              | ((u64)(row)[w] << 2) \
                              | ((u64)((w < 31 ? (row)[w+1] : 0u) & 3u) << 34) )
            u64 a = EXT5(sS[r]) | EXT5(sS[r + 1]);
            u64 or5 = a | (a >> 1) | (a >> 2) | (a >> 3) | (a >> 4);
            u64 e2 = EXT5(sS[r + 2]);
            u64 or2 = e2 | (e2 >> 1);
            kept = C & ~(unsigned)(or5 | or2);
        }
        unsigned found = 0;
        if (kept) {
            u64 dil = 0;
            #pragma unroll
            for (int rr = 0; rr < 7; ++rr) {
                const unsigned* row = sD[r + rr];
                unsigned L = w ? row[w-1] : 0u;
                unsigned R = (w < 31) ? row[w+1] : 0u;
                dil |= (u64)(L >> 25) | ((u64)row[w] << 7) | ((u64)(R & 0x7Fu) << 39);
            }
            u64 a2 = dil | (dil >> 1);
            u64 b2 = a2 | (a2 >> 2);
            u64 c2 = b2 | (b2 >> 4);
            u64 o15 = c2 | (c2 >> 7);
            found = kept & (unsigned)o15;
        }
        sMask[r][w] = found;
        int nf = __popc(found);
        if (nf) {
            int base = atomicAdd(&lcnt[0], nf);
            unsigned fi = found;
            while (fi) {
                int bit = __builtin_ctz(fi); fi &= fi - 1;
                if (base < 256) sPtXY[base] = (unsigned)((r << 10) | (w << 5) | bit);
                ++base;
            }
        }
    }
    __syncthreads();
    int nPts = lcnt[0]; if (nPts > 256) nPts = 256;

    // P2: one thread per point — window extract + minr + pair emission
    for (int i = t; i < nPts; i += 256) {
        unsigned e = sPtXY[i];
        int r = e >> 10, x = (int)(e & 1023u);
        int y = y0 + r;
        int x7 = x - 7;
        int j = x7 >> 5;
        int sh = x7 & 31;
        u64 lo = 0, hi = 0;
        #pragma unroll
        for (int rr = 0; rr < 7; ++rr) {
            const unsigned* row = sD[r + rr];
            unsigned W0 = (j >= 0) ? row[j] : 0u;
            unsigned W1 = (j + 1 < 32) ? row[j + 1] : 0u;
            u64 win = (((u64)W0 | ((u64)W1 << 32)) >> sh) & 0x7FFFull;
            if (rr < 4) lo |= win << (15 * rr);
            else        hi |= win << (15 * (rr - 4));
        }
        int minr = NQ - 1;
        while (lo) { int bb2 = __builtin_ctzll(lo); lo &= lo - 1; int rk = prank[bb2];      if (rk < minr) minr = rk; }
        while (hi) { int bb2 = __builtin_ctzll(hi); hi &= hi - 1; int rk = prank[60 + bb2]; if (rk < minr) minr = rk; }
        int vx = sdxv[minr], vy = sdyv[minr];

        ((unsigned char*)sVB)[(r << 10) + x] =
            (unsigned char)((vx + 7) | ((vy + 3) << 4));
        sPk[i] = (unsigned)x | ((unsigned)y << 10)
               | ((unsigned)(vx + 7) << 19) | ((unsigned)(vy + 3) << 23);

        int txl = x - RR; txl = (txl < 0 ? 0 : txl) >> 6;
        int txh = x + RR; txh = (txh > WW - 1 ? WW - 1 : txh) >> 6;
        int tyl = y - RR; tyl = (tyl < 0 ? 0 : tyl) >> 5;
        int tyh = y + RR; tyh = (tyh > HH - 1 ? HH - 1 : tyh) >> 5;
        int np = (txh - txl + 1) * (tyh - tyl + 1);
        int base = atomicAdd(&lcnt[1], np);
        for (int ty = tyl; ty <= tyh; ++ty)
            for (int tx = txl; tx <= txh; ++tx) {
                if (base < 1024)
                    sPairs[base] = ((unsigned)i << 16) | (unsigned)(b * TPB + ty * TXN + tx);
                ++base;
            }
    }
    __syncthreads();
    int nPairs = lcnt[1]; if (nPairs > 1024) nPairs = 1024;

    // P3: parallel independent atomics
    for (int jj = t; jj < nPairs; jj += 256) {
        unsigned pr = sPairs[jj];
        int tile = (int)(pr & 0xFFFFu);
        int i    = (int)(pr >> 16);
        int pos = atomicAdd(&cnt[tile], 1);
        if (pos < cap) lists[(size_t)tile * cap + pos] = sPk[i];
    }

    // store phase: thread t covers px 4t..4t+3 of each of the 4 rows
    int xs = t << 2;
    int wq = t >> 3;
    int bo = xs & 31;
    size_t bbase = (size_t)b * HH * WW;
    #pragma unroll
    for (int g = 0; g < 4; ++g) {
        unsigned mw = sMask[g][wq];
        unsigned vb = sVB[g][t];
        float fy = (float)(y0 + g);
        float4 o2, o3, o4, o5;
        float* po2 = &o2.x; float* po3 = &o3.x; float* po4 = &o4.x; float* po5 = &o5.x;
        #pragma unroll
        for (int jj = 0; jj < 4; ++jj) {
            float fm = (float)((mw >> (bo + jj)) & 1u);
            unsigned by = (vb >> (8 * jj)) & 255u;
            float fvx = (float)((int)(by & 15u) - 7);
            float fvy = (float)((int)(by >> 4) - 3);
            float fx = (float)(xs + jj);
            po2[jj] = fx * fm;
            po3[jj] = fy * fm;
            po4[jj] = (fx + fvx) * fm;
            po5[jj] = (fy + fvy) * fm;
        }
        size_t idx = bbase + (size_t)(y0 + g) * WW + xs;
        *reinterpret_cast<float4*>(out + 2 * (size_t)N_PIX + idx) = o2;
        *reinterpret_cast<float4*>(out + 3 * (size_t)N_PIX + idx) = o3;
        *reinterpret_cast<float4*>(out + 4 * (size_t)N_PIX + idx) = o4;
        *reinterpret_cast<float4*>(out + 5 * (size_t)N_PIX + idx) = o5;
    }
}

// ---- kernel 3: 64x32-tile gather-splat; pk-f32 accumulation ----
__global__ __launch_bounds__(256, 4) void splat_finalize(
    const int* __restrict__ cnt, const unsigned* __restrict__ lists,
    const float* __restrict__ wtab_g,
    float* __restrict__ out, int cap)
{
    __shared__ __align__(16) float wtab[WTABN];
    __shared__ __align__(16) unsigned pts[CAP_MAX];
    int t = threadIdx.x;

    const float4* wg = (const float4*)wtab_g;
    #pragma unroll
    for (int i = 0; i < WTABN / 1024; ++i)
        ((float4*)wtab)[i * 256 + t] = wg[i * 256 + t];
    if (t < (WTABN / 4) % 256)                       // 2016 = 7*256 + 224
        ((float4*)wtab)[(WTABN / 1024) * 256 + t] = wg[(WTABN / 1024) * 256 + t];

    int txT = blockIdx.x, tyT = blockIdx.y, b = blockIdx.z;
    int tile = b * TPB + tyT * TXN + txT;
    int n = cnt[tile]; if (n > cap) n = cap;
    int n4 = (n + 3) & ~3;
    for (int i = t; i < n4; i += 256)
        pts[i] = (i < n) ? lists[(size_t)tile * cap + i] : 0xFFFFFFFFu;  // py=511 sentinel
    __syncthreads();

    int x0  = txT * TLW + (t & 15) * 4;
    int y0t = tyT * TLH + (t >> 4) * 2;                       // rows y0t, y0t+1
    int wy0 = tyT * TLH + __builtin_amdgcn_readfirstlane(t >> 6) * 8;  // wave strip

    v2f a0p[2][2] = {};          // a0 col-pairs: [ry][0]=(c0,c1) [ry][1]=(c2,c3)
    v2f av[2][4]  = {};          // (a1,a2) per [ry][col]

    for (int p = 0; p < n4; p += 4) {
        uint4 P = *(const uint4*)&pts[p];
        #pragma unroll
        for (int k = 0; k < 4; ++k) {
            int spk = __builtin_amdgcn_readfirstlane(
                (int)(k == 0 ? P.x : k == 1 ? P.y : k == 2 ? P.z : P.w));
            int py = (spk >> 10) & 511;
            if (py < wy0 - 20 || py > wy0 + 27) continue;     // scalar y-skip
            int px = spk & 1023;
            float pvx = (float)(((spk >> 19) & 15) - 7);
            float pvy = (float)(((spk >> 23) & 7) - 3);
            v2f vv = {pvx, pvy};

            int coff = px - x0 + 21;                          // col3's padded idx
            coff = coff < 0 ? 0 : (coff > 45 ? 45 : coff);
            int rot = coff & 3;
            int cb  = rot * (42 * 48) + (coff & ~3);
            #pragma unroll
            for (int ry = 0; ry < 2; ++ry) {
                int dyr = py - (y0t + ry) + 20;
                int rowi = ((unsigned)dyr > 40u) ? 41 : dyr;  // row 41 = zeros
                float4 wv = *(const float4*)&wtab[cb + rowi * 48];
                // col j uses element (3-j)
                a0p[ry][0] += (v2f){wv.w, wv.z};
                a0p[ry][1] += (v2f){wv.y, wv.x};
                av[ry][0] += wv.w * vv;
                av[ry][1] += wv.z * vv;
                av[ry][2] += wv.y * vv;
                av[ry][3] += wv.x * vv;
            }
        }
    }

    size_t bbase = (size_t)b * HH * WW;
    #pragma unroll
    for (int ry = 0; ry < 2; ++ry) {
        int y = y0t + ry;
        size_t idx = bbase + (size_t)y * WW + x0;
        float d0 = a0p[ry][0].x + 1.6f, d1 = a0p[ry][0].y + 1.6f;
        float d2 = a0p[ry][1].x + 1.6f, d3 = a0p[ry][1].y + 1.6f;
        float4 ox = { (float)x0     + av[ry][0].x / d0, (float)(x0+1) + av[ry][1].x / d1,
                      (float)(x0+2) + av[ry][2].x / d2, (float)(x0+3) + av[ry][3].x / d3 };
        float4 oy = { (float)y + av[ry][0].y / d0, (float)y + av[ry][1].y / d1,
                      (float)y + av[ry][2].y / d2, (float)y + av[ry][3].y / d3 };
        *reinterpret_cast<float4*>(out + idx)                 = ox;
        *reinterpret_cast<float4*>(out + (size_t)N_PIX + idx) = oy;
    }
}

extern "C" void kernel_launch(void* const* d_in, const int* in_sizes, int n_in,
                              void* d_out, int out_size, void* d_ws, size_t ws_size,
                              hipStream_t stream) {
    const float* src = (const float*)d_in[0];
    const float* dst = (const float*)d_in[1];
    const float* xx  = (const float*)d_in[2];
    const float* yy  = (const float*)d_in[3];
    float* out = (float*)d_out;

    int*      cnt    = (int*)d_ws;
    unsigned* packed = (unsigned*)((char*)d_ws + PACK_OFF);
    float*    wtab_g = (float*)((char*)d_ws + WTAB_OFF);
    unsigned* lists  = (unsigned*)((char*)d_ws + LISTS_OFF);

    int cap = CAP_MAX;
    size_t need = (size_t)LISTS_OFF + (size_t)N_TILES * cap * sizeof(unsigned);
    if (ws_size < need) {
        long avail = ((long)ws_size - LISTS_OFF) / ((long)N_TILES * 4);
        cap = avail < 1 ? 1 : (avail > CAP_MAX ? CAP_MAX : (int)avail);
    }

    pack_zero<<<(2 * N_PIX / 4) / 256, 256, 0, stream>>>(src, dst, packed, cnt, wtab_g);

    dim3 g1(HH / 4, BB);
    build_points<<<g1, 256, 0, stream>>>(packed, xx, yy, out, cnt, lists, cap);

    dim3 g2(TXN, TYN, BB);
    splat_finalize<<<g2, 256, 0, stream>>>(cnt, lists, wtab_g, out, cap);
}

// Round 6
// 138.406 us; speedup vs baseline: 2.2230x; 1.0829x over previous
//
#include <hip/hip_runtime.h>

// BNMorph forward — pointize build + wave-compacted gather-splat (64x32 tiles).
// B=8, H=320, W=1024. Outputs (concat, f32, each [B,H,W]):
//   0 morphedx, 1 morphedy, 2 orgpts_x, 3 orgpts_y, 4 correspts_x, 5 correspts_y

#define BB 8
#define HH 320
#define WW 1024
#define N_PIX (BB*HH*WW)            // 2,621,440
#define WPI (HH*(WW/32))            // 10240 words per image
#define RR 20
#define TLW 64
#define TLH 32
#define TXN (WW/TLW)                // 16
#define TYN (HH/TLH)                // 10
#define TPB (TXN*TYN)               // 160
#define N_TILES (BB*TPB)            // 1280
#define NQ 105
#define CAP_MAX 512
#define PACK_OFF 16384
#define WTABN (4*42*48)             // 8064 floats
#define WTAB_OFF (PACK_OFF + 2*BB*WPI*4)     // 671744 (16B aligned)
#define LISTS_OFF (WTAB_OFF + WTABN*4)       // 704000 (16B aligned)

typedef unsigned long long u64;
typedef float v2f __attribute__((ext_vector_type(2)));

// ---- kernel 1: pack maps to bitmasks + zero counters + build weight table ----
__global__ __launch_bounds__(256) void pack_zero(
    const float* __restrict__ src, const float* __restrict__ dst,
    unsigned* __restrict__ packed, int* __restrict__ cnt,
    float* __restrict__ wtab_g)
{
    int t = threadIdx.x;
    int i = blockIdx.x * 256 + t;           // float4 index in [0, 2*N_PIX/4)
    if (i < N_TILES) cnt[i] = 0;
    if (i < WTABN) {                        // rotated-padded weight table
        int rot = i / (42 * 48);
        int rem = i - rot * (42 * 48);
        int row = rem / 48, c = rem - row * 48;
        int pc = c + rot;
        float v = 0.0f;
        if (row <= 40 && pc >= 4 && pc <= 44) {
            int dxv = pc - 24, dyv = row - 20;
            float d = sqrtf((float)(dxv * dxv + dyv * dyv));
            v = 0.7f * expf((-d * 1.9f) / 24.0f);
        }
        wtab_g[i] = v;
    }
    const float4* p = (i < (N_PIX >> 2)) ? (const float4*)src + i
                                         : (const float4*)dst + (i - (N_PIX >> 2));
    float4 v = *p;
    unsigned nib = (v.x > 0.5f ? 1u : 0u) | (v.y > 0.5f ? 2u : 0u)
                 | (v.z > 0.5f ? 4u : 0u) | (v.w > 0.5f ? 8u : 0u);
    unsigned val = nib << ((t & 7) * 4);
    val |= __shfl_xor(val, 1);
    val |= __shfl_xor(val, 2);
    val |= __shfl_xor(val, 4);
    if ((t & 7) == 0) packed[i >> 3] = val;
}

// ---- kernel 2: point finding only (no dense stores), 2 rows/block ----
// grid (160, 8) = 1280 blocks.
__global__ __launch_bounds__(256) void build_points(
    const unsigned* __restrict__ packed,
    const float* __restrict__ xx, const float* __restrict__ yy,
    int* __restrict__ cnt, unsigned* __restrict__ lists, int cap)
{
    __shared__ unsigned sS[4][32];     // src rows y0-2 .. y0+1
    __shared__ unsigned sD[8][32];     // dst rows y0-3 .. y0+4
    __shared__ unsigned sPtXY[128];    // compacted found px: (r<<10)|x
    __shared__ unsigned sPk[128];      // packed point records
    __shared__ unsigned sPairs[512];   // (ptIdx<<16)|tile
    __shared__ int prank[NQ], sdxv[NQ], sdyv[NQ];
    __shared__ int lcnt[2];

    int t  = threadIdx.x;
    int y0 = blockIdx.x * 2;
    int b  = blockIdx.y;
    const unsigned* psrc = packed + (size_t)b * WPI;
    const unsigned* pdst = packed + (size_t)(BB + b) * WPI;

    {
        int r = t >> 5, w = t & 31;             // r 0..7 for sD
        int y2 = y0 - 3 + r;
        sD[r][w] = (y2 >= 0 && y2 < HH) ? pdst[(y2 << 5) + w] : 0u;
        if (t < 128) {
            int y3 = y0 - 2 + (t >> 5);         // rows y0-2..y0+1 < 320
            sS[t >> 5][w] = (y3 >= 0) ? psrc[(y3 << 5) + w] : 0u;
        }
    }
    if (t < NQ) {
        int dx = (int)xx[t], dy = (int)yy[t];
        sdxv[t] = dx; sdyv[t] = dy;
        prank[(dy + 3) * 15 + (dx + 7)] = t;
    }
    if (t < 2) lcnt[t] = 0;
    __syncthreads();

    // P1: bit-parallel kept/found masks + compaction (2 rows x 32 words)
    if (t < 64) {
        int r = t >> 5, w = t & 31;
        unsigned C = sS[r + 2][w];
        unsigned kept = 0;
        if (C) {
            #define EXT5(row) ( (u64)((w ? (row)[w-1] : 0u) >> 30) \
                              | ((u64)(row)[w] << 2) \
                              | ((u64)((w < 31 ? (row)[w+1] : 0u) & 3u) << 34) )
            u64 a = EXT5(sS[r]) | EXT5(sS[r + 1]);
            u64 or5 = a | (a >> 1) | (a >> 2) | (a >> 3) | (a >> 4);
            u64 e2 = EXT5(sS[r + 2]);
            u64 or2 = e2 | (e2 >> 1);
            kept = C & ~(unsigned)(or5 | or2);
        }
        unsigned found = 0;
        if (kept) {
            u64 dil = 0;
            #pragma unroll
            for (int rr = 0; rr < 7; ++rr) {
                const unsigned* row = sD[r + rr];
                unsigned L = w ? row[w-1] : 0u;
                unsigned R = (w < 31) ? row[w+1] : 0u;
                dil |= (u64)(L >> 25) | ((u64)row[w] << 7) | ((u64)(R & 0x7Fu) << 39);
            }
            u64 a2 = dil | (dil >> 1);
            u64 b2 = a2 | (a2 >> 2);
            u64 c2 = b2 | (b2 >> 4);
            u64 o15 = c2 | (c2 >> 7);
            found = kept & (unsigned)o15;
        }
        int nf = __popc(found);
        if (nf) {
            int base = atomicAdd(&lcnt[0], nf);
            unsigned fi = found;
            while (fi) {
                int bit = __builtin_ctz(fi); fi &= fi - 1;
                if (base < 128) sPtXY[base] = (unsigned)((r << 10) | (w << 5) | bit);
                ++base;
            }
        }
    }
    __syncthreads();
    int nPts = lcnt[0]; if (nPts > 128) nPts = 128;

    // P2: one thread per point — window extract + minr + pair emission
    if (t < nPts) {
        unsigned e = sPtXY[t];
        int r = e >> 10, x = (int)(e & 1023u);
        int y = y0 + r;
        int x7 = x - 7;
        int j = x7 >> 5;
        int sh = x7 & 31;
        u64 lo = 0, hi = 0;
        #pragma unroll
        for (int rr = 0; rr < 7; ++rr) {
            const unsigned* row = sD[r + rr];
            unsigned W0 = (j >= 0) ? row[j] : 0u;
            unsigned W1 = (j + 1 < 32) ? row[j + 1] : 0u;
            u64 win = (((u64)W0 | ((u64)W1 << 32)) >> sh) & 0x7FFFull;
            if (rr < 4) lo |= win << (15 * rr);
            else        hi |= win << (15 * (rr - 4));
        }
        int minr = NQ - 1;
        while (lo) { int bb2 = __builtin_ctzll(lo); lo &= lo - 1; int rk = prank[bb2];      if (rk < minr) minr = rk; }
        while (hi) { int bb2 = __builtin_ctzll(hi); hi &= hi - 1; int rk = prank[60 + bb2]; if (rk < minr) minr = rk; }
        int vx = sdxv[minr], vy = sdyv[minr];

        sPk[t] = (unsigned)x | ((unsigned)y << 10)
               | ((unsigned)(vx + 7) << 19) | ((unsigned)(vy + 3) << 23);

        int txl = x - RR; txl = (txl < 0 ? 0 : txl) >> 6;
        int txh = x + RR; txh = (txh > WW - 1 ? WW - 1 : txh) >> 6;
        int tyl = y - RR; tyl = (tyl < 0 ? 0 : tyl) >> 5;
        int tyh = y + RR; tyh = (tyh > HH - 1 ? HH - 1 : tyh) >> 5;
        int np = (txh - txl + 1) * (tyh - tyl + 1);
        int base = atomicAdd(&lcnt[1], np);
        for (int ty = tyl; ty <= tyh; ++ty)
            for (int tx = txl; tx <= txh; ++tx) {
                if (base < 512)
                    sPairs[base] = ((unsigned)t << 16) | (unsigned)(b * TPB + ty * TXN + tx);
                ++base;
            }
    }
    __syncthreads();
    int nPairs = lcnt[1]; if (nPairs > 512) nPairs = 512;

    // P3: parallel independent global atomics
    for (int jj = t; jj < nPairs; jj += 256) {
        unsigned pr = sPairs[jj];
        int tile = (int)(pr & 0xFFFFu);
        int i    = (int)(pr >> 16);
        int pos = atomicAdd(&cnt[tile], 1);
        if (pos < cap) lists[(size_t)tile * cap + pos] = sPk[i];
    }
}

// ---- kernel 3: wave-compacted gather-splat; writes ALL 6 planes ----
__global__ __launch_bounds__(256, 4) void splat_finalize(
    const int* __restrict__ cnt, const unsigned* __restrict__ lists,
    const float* __restrict__ wtab_g,
    float* __restrict__ out, int cap)
{
    __shared__ __align__(16) float wtab[WTABN];      // 32.25 KB
    __shared__ __align__(16) unsigned sWav[4][264];  // per-wave strip lists
    int t = threadIdx.x;
    int lane = t & 63, w = t >> 6;

    for (int i = t; i < WTABN / 4; i += 256)
        ((float4*)wtab)[i] = ((const float4*)wtab_g)[i];

    int txT = blockIdx.x, tyT = blockIdx.y, b = blockIdx.z;
    int tile = b * TPB + tyT * TXN + txT;
    const unsigned* lp = lists + (size_t)tile * cap;
    int n = cnt[tile]; if (n > cap) n = cap;

    // per-wave compaction: keep points with py in [wy0-20, wy0+27]
    int wy0 = tyT * TLH + w * 8;
    int cw = 0;
    for (int base = 0; base < n; base += 64) {
        int i = base + lane;
        unsigned pk = 0xFFFFFFFFu;
        if (i < n) pk = lp[i];
        int py = (int)((pk >> 10) & 511u);
        bool pass = (i < n) & (py >= wy0 - 20) & (py <= wy0 + 27);
        u64 m = __ballot(pass);
        if (pass) {
            int idx = __popcll(m & ((1ull << lane) - 1ull));
            if (cw + idx < 256) sWav[w][cw + idx] = pk;
        }
        cw += __popcll(m);
    }
    if (cw > 256) cw = 256;
    int c4 = (cw + 3) & ~3;
    if (lane < c4 - cw) sWav[w][cw + lane] = 0xFFFFFFFFu;   // py=511 sentinel
    __syncthreads();

    int x0  = txT * TLW + (t & 15) * 4;
    int y0t = tyT * TLH + (t >> 4) * 2;     // rows y0t, y0t+1

    v2f a0p[2][2] = {};          // a0 col-pairs: [ry][0]=(c0,c1) [ry][1]=(c2,c3)
    v2f av[2][4]  = {};          // (a1,a2) per [ry][col]

    for (int p = 0; p < c4; p += 4) {
        uint4 P = *(const uint4*)&sWav[w][p];
        #pragma unroll
        for (int k = 0; k < 4; ++k) {
            int spk = __builtin_amdgcn_readfirstlane(
                (int)(k == 0 ? P.x : k == 1 ? P.y : k == 2 ? P.z : P.w));
            int pxp21 = (spk & 1023) + 21;
            int pyp20 = ((spk >> 10) & 511) + 20;
            float pvx = (float)(((spk >> 19) & 15) - 7);
            float pvy = (float)(((spk >> 23) & 7) - 3);
            v2f vv = {pvx, pvy};

            int coff = pxp21 - x0;
            coff = coff < 0 ? 0 : (coff > 45 ? 45 : coff);
            int rot = coff & 3;
            int cb  = rot * (42 * 48) + (coff & ~3);
            #pragma unroll
            for (int ry = 0; ry < 2; ++ry) {
                int dyr = pyp20 - (y0t + ry);
                int rowi = ((unsigned)dyr > 40u) ? 41 : dyr;  // row 41 = zeros
                float4 wv = *(const float4*)&wtab[cb + rowi * 48];
                a0p[ry][0] += (v2f){wv.w, wv.z};
                a0p[ry][1] += (v2f){wv.y, wv.x};
                av[ry][0] += wv.w * vv;
                av[ry][1] += wv.z * vv;
                av[ry][2] += wv.y * vv;
                av[ry][3] += wv.x * vv;
            }
        }
    }

    // epilogue: morphed + zero-init planes 2..5
    size_t bbase = (size_t)b * HH * WW;
    float4 z4 = {0.f, 0.f, 0.f, 0.f};
    #pragma unroll
    for (int ry = 0; ry < 2; ++ry) {
        int y = y0t + ry;
        size_t idx = bbase + (size_t)y * WW + x0;
        float d0 = a0p[ry][0].x + 1.6f, d1 = a0p[ry][0].y + 1.6f;
        float d2 = a0p[ry][1].x + 1.6f, d3 = a0p[ry][1].y + 1.6f;
        float4 ox = { (float)x0     + av[ry][0].x / d0, (float)(x0+1) + av[ry][1].x / d1,
                      (float)(x0+2) + av[ry][2].x / d2, (float)(x0+3) + av[ry][3].x / d3 };
        float4 oy = { (float)y + av[ry][0].y / d0, (float)y + av[ry][1].y / d1,
                      (float)y + av[ry][2].y / d2, (float)y + av[ry][3].y / d3 };
        *reinterpret_cast<float4*>(out + idx)                     = ox;
        *reinterpret_cast<float4*>(out + (size_t)N_PIX + idx)     = oy;
        *reinterpret_cast<float4*>(out + 2 * (size_t)N_PIX + idx) = z4;
        *reinterpret_cast<float4*>(out + 3 * (size_t)N_PIX + idx) = z4;
        *reinterpret_cast<float4*>(out + 4 * (size_t)N_PIX + idx) = z4;
        *reinterpret_cast<float4*>(out + 5 * (size_t)N_PIX + idx) = z4;
    }
    __syncthreads();

    // scatter org/corres values for points inside this tile
    int tx0 = txT * TLW, ty0 = tyT * TLH;
    for (int i = t; i < n; i += 256) {
        unsigned pk = lp[i];
        int px = (int)(pk & 1023u);
        int py = (int)((pk >> 10) & 511u);
        if (px >= tx0 && px < tx0 + TLW && py >= ty0 && py < ty0 + TLH) {
            int vx = (int)((pk >> 19) & 15u) - 7;
            int vy = (int)((pk >> 23) & 7u) - 3;
            size_t idx = bbase + (size_t)py * WW + px;
            out[2 * (size_t)N_PIX + idx] = (float)px;
            out[3 * (size_t)N_PIX + idx] = (float)py;
            out[4 * (size_t)N_PIX + idx] = (float)(px + vx);
            out[5 * (size_t)N_PIX + idx] = (float)(py + vy);
        }
    }
}

extern "C" void kernel_launch(void* const* d_in, const int* in_sizes, int n_in,
                              void* d_out, int out_size, void* d_ws, size_t ws_size,
                              hipStream_t stream) {
    const float* src = (const float*)d_in[0];
    const float* dst = (const float*)d_in[1];
    const float* xx  = (const float*)d_in[2];
    const float* yy  = (const float*)d_in[3];
    float* out = (float*)d_out;

    int*      cnt    = (int*)d_ws;
    unsigned* packed = (unsigned*)((char*)d_ws + PACK_OFF);
    float*    wtab_g = (float*)((char*)d_ws + WTAB_OFF);
    unsigned* lists  = (unsigned*)((char*)d_ws + LISTS_OFF);

    int cap = CAP_MAX;
    size_t need = (size_t)LISTS_OFF + (size_t)N_TILES * cap * sizeof(unsigned);
    if (ws_size < need) {
        long avail = ((long)ws_size - LISTS_OFF) / ((long)N_TILES * 4);
        cap = avail < 1 ? 1 : (avail > CAP_MAX ? CAP_MAX : (int)avail);
    }

    pack_zero<<<(2 * N_PIX / 4) / 256, 256, 0, stream>>>(src, dst, packed, cnt, wtab_g);

    dim3 g1(HH / 2, BB);
    build_points<<<g1, 256, 0, stream>>>(packed, xx, yy, cnt, lists, cap);

    dim3 g2(TXN, TYN, BB);
    splat_finalize<<<g2, 256, 0, stream>>>(cnt, lists, wtab_g, out, cap);
}